// Round 1
// baseline (843.369 us; speedup 1.0000x reference)
//
#include <hip/hip_runtime.h>

#define N_VOX 200000
#define KOFF 27
#define PPK 100000
#define C 64
#define BN_EPS 1e-5f

// ---------------------------------------------------------------------------
// Conv: gather -> per-offset GEMM -> scatter-add (atomics) into `out`.
// One wave processes one rulebook pair at a time; lane = output channel.
// W[k][:,lane] held in 64 VGPRs (loop-invariant per block). Feature row is
// wave-uniform (address from readlane'd index) -> scalar/broadcast loads,
// inner loop is pure v_fmac. 4 accumulator chains to break the fmac
// dependency chain (64x4cy latency -> ~128cy throughput).
// ---------------------------------------------------------------------------
__global__ __launch_bounds__(256, 2)
void conv_kernel(const float* __restrict__ features,
                 const float* __restrict__ weight,
                 const int* __restrict__ in_idx,
                 const int* __restrict__ out_idx,
                 float* __restrict__ out,
                 int pairs_per_block)
{
    const int k    = blockIdx.y;
    const int lane = threadIdx.x & 63;
    const int wave = threadIdx.x >> 6;

    // Load W[k][:, lane] into registers (coalesced: consecutive lanes ->
    // consecutive addresses).
    const float* Wk = weight + (size_t)k * C * C;
    float w[64];
#pragma unroll
    for (int i = 0; i < 64; ++i) w[i] = Wk[i * C + lane];

    const int chunk_base = blockIdx.x * pairs_per_block;
    const int chunk_end  = min(chunk_base + pairs_per_block, PPK);
    const int kbase      = k * PPK;

    // Each wave grabs groups of 64 pairs (strided across the 4 waves).
    for (int gbase = chunk_base + wave * 64; gbase < chunk_end; gbase += 4 * 64) {
        const int nrem = min(64, chunk_end - gbase);
        int in_v = 0, out_v = 0;
        if (lane < nrem) {
            in_v  = in_idx[kbase + gbase + lane];   // coalesced
            out_v = out_idx[kbase + gbase + lane];  // coalesced
        }
        for (int j = 0; j < nrem; ++j) {
            const int in_u  = __builtin_amdgcn_readlane(in_v, j);
            const int out_u = __builtin_amdgcn_readlane(out_v, j);
            const float* frow = features + (size_t)in_u * C;  // wave-uniform addr
            float a0 = 0.f, a1 = 0.f, a2 = 0.f, a3 = 0.f;
#pragma unroll
            for (int i = 0; i < 64; i += 4) {
                a0 += frow[i + 0] * w[i + 0];
                a1 += frow[i + 1] * w[i + 1];
                a2 += frow[i + 2] * w[i + 2];
                a3 += frow[i + 3] * w[i + 3];
            }
            const float acc = (a0 + a1) + (a2 + a3);
            // Native global_atomic_add_f32 (not a CAS loop).
            unsafeAtomicAdd(&out[(size_t)out_u * C + lane], acc);
        }
    }
}

// ---------------------------------------------------------------------------
// Per-channel sum / sum-of-squares of the conv output (pre-bias; bias cancels
// under BN so it is never added). stats[0..63]=sum, stats[64..127]=sumsq.
// ---------------------------------------------------------------------------
__global__ __launch_bounds__(256)
void stats_kernel(const float* __restrict__ out,
                  float* __restrict__ stats,
                  int rows_per_block)
{
    __shared__ float ssum[256];
    __shared__ float ssq[256];
    const int c   = threadIdx.x & 63;
    const int sub = threadIdx.x >> 6;  // 0..3 (wave id)
    const int row0 = blockIdx.x * rows_per_block;
    const int row1 = min(row0 + rows_per_block, N_VOX);
    float s = 0.f, q = 0.f;
    for (int r = row0 + sub; r < row1; r += 4) {   // each wave reads full rows, coalesced
        const float v = out[(size_t)r * C + c];
        s += v;
        q += v * v;
    }
    ssum[threadIdx.x] = s;
    ssq[threadIdx.x]  = q;
    __syncthreads();
    if (sub == 0) {
        s = ssum[c] + ssum[64 + c] + ssum[128 + c] + ssum[192 + c];
        q = ssq[c]  + ssq[64 + c]  + ssq[128 + c]  + ssq[192 + c];
        unsafeAtomicAdd(&stats[c], s);
        unsafeAtomicAdd(&stats[64 + c], q);
    }
}

// ---------------------------------------------------------------------------
// Fold BN into per-channel scale/shift. Conv bias cancels:
//   (x + b) - mean(x + b) == x - mean(x), var unchanged.
// ss[0..63]=scale, ss[64..127]=shift.
// ---------------------------------------------------------------------------
__global__ void finalize_params(const float* __restrict__ stats,
                                const float* __restrict__ gamma,
                                const float* __restrict__ beta,
                                float* __restrict__ ss)
{
    const int c = threadIdx.x;
    const float inv_n = 1.0f / (float)N_VOX;
    const float mean  = stats[c] * inv_n;
    const float var   = stats[64 + c] * inv_n - mean * mean;
    const float scale = rsqrtf(var + BN_EPS) * gamma[c];
    ss[c]      = scale;
    ss[64 + c] = beta[c] - mean * scale;
}

// ---------------------------------------------------------------------------
// Apply y = relu(x*scale + shift), in place on `out`, float4-vectorized.
// idx covers float4 elements; channel group = idx & 15 (since 64/4 == 16).
// ---------------------------------------------------------------------------
__global__ __launch_bounds__(256)
void norm_kernel(float* __restrict__ out, const float* __restrict__ ss)
{
    const size_t total4 = (size_t)N_VOX * C / 4;
    const size_t idx = (size_t)blockIdx.x * blockDim.x + threadIdx.x;
    if (idx >= total4) return;
    const int c4 = (int)(idx & 15);
    float4 v = ((const float4*)out)[idx];
    const float4 sc = ((const float4*)ss)[c4];
    const float4 sh = ((const float4*)(ss + 64))[c4];
    v.x = fmaxf(v.x * sc.x + sh.x, 0.f);
    v.y = fmaxf(v.y * sc.y + sh.y, 0.f);
    v.z = fmaxf(v.z * sc.z + sh.z, 0.f);
    v.w = fmaxf(v.w * sc.w + sh.w, 0.f);
    ((float4*)out)[idx] = v;
}

extern "C" void kernel_launch(void* const* d_in, const int* in_sizes, int n_in,
                              void* d_out, int out_size, void* d_ws, size_t ws_size,
                              hipStream_t stream)
{
    const float* features = (const float*)d_in[0];  // [N_VOX, 64]
    const float* weight   = (const float*)d_in[1];  // [27, 64, 64]
    // d_in[2] = bias: unused — cancels exactly under BatchNorm.
    const float* gamma    = (const float*)d_in[3];  // [64]
    const float* beta     = (const float*)d_in[4];  // [64]
    const int*   in_idx   = (const int*)d_in[5];    // [27, 100000]
    const int*   out_idx  = (const int*)d_in[6];    // [27, 100000]
    float* out   = (float*)d_out;                   // [N_VOX, 64]
    float* stats = (float*)d_ws;                    // [128] sums / sumsq
    float* ss    = stats + 128;                     // [128] scale / shift

    // d_out and d_ws are poisoned 0xAA before every launch — zero what we
    // accumulate into.
    hipMemsetAsync(out, 0, (size_t)N_VOX * C * sizeof(float), stream);
    hipMemsetAsync(stats, 0, 128 * sizeof(float), stream);

    const int ppb = 2048;  // pairs per block -> grid (49, 27) = 1323 blocks
    dim3 cgrid((PPK + ppb - 1) / ppb, KOFF);
    conv_kernel<<<cgrid, 256, 0, stream>>>(features, weight, in_idx, out_idx, out, ppb);

    const int rpb = (N_VOX + 255) / 256;  // 782 rows per block, 256 blocks
    stats_kernel<<<256, 256, 0, stream>>>(out, stats, rpb);

    finalize_params<<<1, 64, 0, stream>>>(stats, gamma, beta, ss);

    const size_t total4 = (size_t)N_VOX * C / 4;   // 3.2M float4s
    const int nb = (int)((total4 + 255) / 256);    // 12500 blocks
    norm_kernel<<<nb, 256, 0, stream>>>(out, ss);
}

// Round 2
// 735.544 us; speedup vs baseline: 1.1466x; 1.1466x over previous
//
#include <hip/hip_runtime.h>
#include <hip/hip_bf16.h>

#define N_VOX 200000
#define KOFF 27
#define PPK 100000
#define C 64
#define BN_EPS 1e-5f

typedef __bf16 bf16x8 __attribute__((ext_vector_type(8)));
typedef __bf16 bf16x4 __attribute__((ext_vector_type(4)));
typedef float f32x4 __attribute__((ext_vector_type(4)));

// ---------------------------------------------------------------------------
// features fp32 -> bf16 (RNE), vectorized: 1 float4 in -> 4 bf16 (8B) out.
// ---------------------------------------------------------------------------
__global__ __launch_bounds__(256)
void convert_features(const float* __restrict__ f, __bf16* __restrict__ fb)
{
    const size_t total4 = (size_t)N_VOX * C / 4;
    const size_t i = (size_t)blockIdx.x * blockDim.x + threadIdx.x;
    if (i >= total4) return;
    const float4 v = ((const float4*)f)[i];
    bf16x4 o;
    o.x = (__bf16)v.x; o.y = (__bf16)v.y; o.z = (__bf16)v.z; o.w = (__bf16)v.w;
    ((bf16x4*)fb)[i] = o;
}

// ---------------------------------------------------------------------------
// weight [k][cin][cout] fp32 -> wt [k][cout][cin] bf16 (transposed so B-frags
// read 8 consecutive cin per lane). 221 KB total — tiny kernel.
// ---------------------------------------------------------------------------
__global__ __launch_bounds__(256)
void convert_weight(const float* __restrict__ w, __bf16* __restrict__ wt)
{
    const int k = blockIdx.x;
    const float* W = w + (size_t)k * C * C;
    __bf16* Wt = wt + (size_t)k * C * C;
    for (int idx = threadIdx.x; idx < C * C; idx += 256) {
        const int ci = idx >> 6, co = idx & 63;
        Wt[co * C + ci] = (__bf16)W[idx];
    }
}

// ---------------------------------------------------------------------------
// Conv via MFMA: per k-offset, tile of 256 pairs per block (4 waves).
//  - gather 256 bf16 feature rows into LDS (coalesced dwordx4, deeply
//    pipelined — replaces round-1's serialized scalar-cache row loads)
//  - GEMM: A[256 pairs x 64 cin] * W[k][64 cin x 64 cout] via
//    mfma_f32_16x16x32_bf16; each wave owns a 64-pair stripe (4x4 frags)
//  - scatter-add epilogue with native global_atomic_add_f32
// LDS A row stride = 72 bf16 (144B): start-bank = 4*(m+q) mod 32 -> even
// 8-slot-per-bank distribution for ds_read_b128 / ds_write_b128 (G4).
// ---------------------------------------------------------------------------
__global__ __launch_bounds__(256)
void conv_mfma(const __bf16* __restrict__ featb, const __bf16* __restrict__ wtb,
               const int* __restrict__ in_idx, const int* __restrict__ out_idx,
               float* __restrict__ out)
{
    constexpr int TP = 256;       // pairs per tile
    constexpr int STRIDE = 72;    // LDS row stride (elements)
    __shared__ __bf16 sA[TP * STRIDE];   // 36.9 KB
    __shared__ int s_out[TP];

    const int k = blockIdx.y;
    const int tile_base = blockIdx.x * TP;
    const int t = threadIdx.x;
    const int lane = t & 63;
    const int wave = t >> 6;
    const int m16 = lane & 15;    // A: pair-row in 16; B: cout; C/D: col
    const int quad = lane >> 4;   // 0..3

    // B fragments from Wt[k][cout][cin]: frag(nt,kc) elem [nt*16+m16][kc*32+quad*8+j]
    const __bf16* Wt = wtb + (size_t)k * C * C;
    bf16x8 bfrag[4][2];
#pragma unroll
    for (int nt = 0; nt < 4; ++nt)
#pragma unroll
        for (int kc = 0; kc < 2; ++kc)
            bfrag[nt][kc] = *(const bf16x8*)(Wt + (nt * 16 + m16) * C + kc * 32 + quad * 8);

    // out indices for the tile
    {
        const int pair = tile_base + t;
        s_out[t] = (pair < PPK) ? out_idx[(size_t)k * PPK + pair] : 0;
    }

    // stage gathered A rows: thread t loads row (t>>3)+32*it, 16B chunk (t&7)
    const int c8 = t & 7;
    const int r0 = t >> 3;
#pragma unroll
    for (int it = 0; it < 8; ++it) {
        const int r = r0 + it * 32;
        const int pair = tile_base + r;
        const int row = (pair < PPK) ? in_idx[(size_t)k * PPK + pair] : 0;
        const float4 v = *(const float4*)(featb + (size_t)row * C + c8 * 8);
        *(float4*)(sA + r * STRIDE + c8 * 8) = v;
    }
    __syncthreads();

    // MFMA: wave owns pairs [wave*64, wave*64+64)
    f32x4 acc[4][4] = {};
    const int mbase = wave * 64;
#pragma unroll
    for (int kc = 0; kc < 2; ++kc) {
        bf16x8 afrag[4];
#pragma unroll
        for (int mt = 0; mt < 4; ++mt)
            afrag[mt] = *(const bf16x8*)(sA + (mbase + mt * 16 + m16) * STRIDE + kc * 32 + quad * 8);
#pragma unroll
        for (int nt = 0; nt < 4; ++nt)
#pragma unroll
            for (int mt = 0; mt < 4; ++mt)
                acc[mt][nt] = __builtin_amdgcn_mfma_f32_16x16x32_bf16(
                    afrag[mt], bfrag[nt][kc], acc[mt][nt], 0, 0, 0);
    }

    // scatter-add: C/D frag lane mapping col=lane&15, row=quad*4+reg
#pragma unroll
    for (int mt = 0; mt < 4; ++mt) {
#pragma unroll
        for (int reg = 0; reg < 4; ++reg) {
            const int r = mbase + mt * 16 + quad * 4 + reg;
            const int pair = tile_base + r;
            if (pair < PPK) {
                const int o = s_out[r];
                float* orow = out + (size_t)o * C + m16;
#pragma unroll
                for (int nt = 0; nt < 4; ++nt)
                    unsafeAtomicAdd(orow + nt * 16, acc[mt][nt][reg]);
            }
        }
    }
}

// ---------------------------------------------------------------------------
// Per-channel sum / sum-of-squares (bias skipped: cancels under BN).
// ---------------------------------------------------------------------------
__global__ __launch_bounds__(256)
void stats_kernel(const float* __restrict__ out,
                  float* __restrict__ stats,
                  int rows_per_block)
{
    __shared__ float ssum[256];
    __shared__ float ssq[256];
    const int c   = threadIdx.x & 63;
    const int sub = threadIdx.x >> 6;
    const int row0 = blockIdx.x * rows_per_block;
    const int row1 = min(row0 + rows_per_block, N_VOX);
    float s = 0.f, q = 0.f;
    for (int r = row0 + sub; r < row1; r += 4) {
        const float v = out[(size_t)r * C + c];
        s += v;
        q += v * v;
    }
    ssum[threadIdx.x] = s;
    ssq[threadIdx.x]  = q;
    __syncthreads();
    if (sub == 0) {
        s = ssum[c] + ssum[64 + c] + ssum[128 + c] + ssum[192 + c];
        q = ssq[c]  + ssq[64 + c]  + ssq[128 + c]  + ssq[192 + c];
        unsafeAtomicAdd(&stats[c], s);
        unsafeAtomicAdd(&stats[64 + c], q);
    }
}

__global__ void finalize_params(const float* __restrict__ stats,
                                const float* __restrict__ gamma,
                                const float* __restrict__ beta,
                                float* __restrict__ ss)
{
    const int c = threadIdx.x;
    const float inv_n = 1.0f / (float)N_VOX;
    const float mean  = stats[c] * inv_n;
    const float var   = stats[64 + c] * inv_n - mean * mean;
    const float scale = rsqrtf(var + BN_EPS) * gamma[c];
    ss[c]      = scale;
    ss[64 + c] = beta[c] - mean * scale;
}

__global__ __launch_bounds__(256)
void norm_kernel(float* __restrict__ out, const float* __restrict__ ss)
{
    const size_t total4 = (size_t)N_VOX * C / 4;
    const size_t idx = (size_t)blockIdx.x * blockDim.x + threadIdx.x;
    if (idx >= total4) return;
    const int c4 = (int)(idx & 15);
    float4 v = ((const float4*)out)[idx];
    const float4 sc = ((const float4*)ss)[c4];
    const float4 sh = ((const float4*)(ss + 64))[c4];
    v.x = fmaxf(v.x * sc.x + sh.x, 0.f);
    v.y = fmaxf(v.y * sc.y + sh.y, 0.f);
    v.z = fmaxf(v.z * sc.z + sh.z, 0.f);
    v.w = fmaxf(v.w * sc.w + sh.w, 0.f);
    ((float4*)out)[idx] = v;
}

extern "C" void kernel_launch(void* const* d_in, const int* in_sizes, int n_in,
                              void* d_out, int out_size, void* d_ws, size_t ws_size,
                              hipStream_t stream)
{
    const float* features = (const float*)d_in[0];
    const float* weight   = (const float*)d_in[1];
    // d_in[2] = bias: cancels under BN, unused.
    const float* gamma    = (const float*)d_in[3];
    const float* beta     = (const float*)d_in[4];
    const int*   in_idx   = (const int*)d_in[5];
    const int*   out_idx  = (const int*)d_in[6];
    float* out = (float*)d_out;

    // workspace layout (all 16B-aligned): featb 25.6MB | wtb 221KB | stats 512B | ss 512B
    __bf16* featb = (__bf16*)d_ws;
    __bf16* wtb   = featb + (size_t)N_VOX * C;
    float*  stats = (float*)(wtb + (size_t)KOFF * C * C);
    float*  ss    = stats + 128;

    hipMemsetAsync(out, 0, (size_t)N_VOX * C * sizeof(float), stream);
    hipMemsetAsync(stats, 0, 128 * sizeof(float), stream);

    const size_t total4 = (size_t)N_VOX * C / 4;
    convert_features<<<(int)((total4 + 255) / 256), 256, 0, stream>>>(features, featb);
    convert_weight<<<KOFF, 256, 0, stream>>>(weight, wtb);

    dim3 cgrid((PPK + 255) / 256, KOFF);   // 391 x 27 tiles
    conv_mfma<<<cgrid, 256, 0, stream>>>(featb, wtb, in_idx, out_idx, out);

    const int rpb = (N_VOX + 511) / 512;   // 391 rows/block, 512 blocks
    stats_kernel<<<512, 256, 0, stream>>>(out, stats, rpb);

    finalize_params<<<1, 64, 0, stream>>>(stats, gamma, beta, ss);

    norm_kernel<<<(int)((total4 + 255) / 256), 256, 0, stream>>>(out, ss);
}